// Round 1
// baseline (145.585 us; speedup 1.0000x reference)
//
#include <hip/hip_runtime.h>

// ws float layout
#define OFF_U0   0        // 1024
#define OFF_U1   1024     // 1024
#define OFF_SY   2048     // 2 (sy0, sy1) ; 2050..2051 pad
#define OFF_S0   2052     // 4096
#define OFF_S1   6148     // 4096
#define OFF_RHS  10244    // 4096  (byte off 40976, 16B aligned)
#define OFF_W2R  14340    // 1024
#define OFF_C    15364    // 1
#define MEMSET_FLOATS 10244  // u0,u1,sy,S0,S1 (atomic targets)

__device__ __forceinline__ float tanh_fast(float x) {
    float e = __expf(x + x);                       // v_mul + v_exp
    return 1.0f - 2.0f * __builtin_amdgcn_rcpf(e + 1.0f);
}

// K1: u_s[h] = sum_a y_s[a]*tanh(qx_s[a]@Wa + ba)[h] ; sy_s = sum_a y_s[a]
// grid = 2*achunks blocks (set-major), 256 thr; each block: 64 quad points, all 1024 h.
__global__ __launch_bounds__(256) void k1(
    const float* __restrict__ qx0, const float* __restrict__ qx1,
    const float* __restrict__ Wa0, const float* __restrict__ Wa1,
    const float* __restrict__ ba0, const float* __restrict__ ba1,
    const float* __restrict__ eqp, float* __restrict__ ws, int achunks)
{
    int bx = blockIdx.x;
    int s  = bx / achunks;
    int ac = bx - s * achunks;
    const float* qx = s ? qx1 : qx0;
    const float* Wa = s ? Wa1 : Wa0;
    const float* ba = s ? ba1 : ba0;
    float* u   = ws + (s ? OFF_U1 : OFF_U0);
    float* syp = ws + OFF_SY + s;

    __shared__ float qL[64][3];
    __shared__ float yL[64];

    int tid = threadIdx.x;
    float eq = eqp[0];
    float my_y = 0.0f;
    if (tid < 64) {
        int a = ac * 64 + tid;
        float q0 = qx[a*3+0], q1 = qx[a*3+1], q2 = qx[a*3+2];
        qL[tid][0] = q0; qL[tid][1] = q1; qL[tid][2] = q2;
        my_y = __expf(-eq * (q0*q0 + q1*q1 + q2*q2));
        yL[tid] = my_y;
    }
    __syncthreads();

    float w0[4], w1[4], w2[4], bb[4], acc[4];
    #pragma unroll
    for (int k = 0; k < 4; ++k) {
        int h = tid + 256*k;
        w0[k] = Wa[h];
        w1[k] = Wa[1024 + h];
        w2[k] = Wa[2048 + h];
        bb[k] = ba[h];
        acc[k] = 0.0f;
    }
    for (int a = 0; a < 64; ++a) {
        float q0 = qL[a][0], q1 = qL[a][1], q2 = qL[a][2];  // LDS broadcast
        float ya = yL[a];
        #pragma unroll
        for (int k = 0; k < 4; ++k) {
            float z = fmaf(q0, w0[k], fmaf(q1, w1[k], fmaf(q2, w2[k], bb[k])));
            acc[k] = fmaf(ya, tanh_fast(z), acc[k]);
        }
    }
    #pragma unroll
    for (int k = 0; k < 4; ++k)
        atomicAdd(&u[tid + 256*k], acc[k]);

    if (tid < 64) {   // wave 0: reduce y partial sum
        float v = my_y;
        #pragma unroll
        for (int off = 32; off > 0; off >>= 1)
            v += __shfl_down(v, off);
        if (tid == 0) atomicAdd(syp, v);
    }
}

// K2: S_s[j] = sum_h u_s[h]*Wb[h,j] + sy_s*bb[j].  The big 2x16MB read.
// grid = 256: s = bx>>7 ; hc = (bx&127)>>2 (32 h-chunks of 32) ; jc = bx&3 (4 j-chunks of 1024)
__global__ __launch_bounds__(256) void k2(
    const float* __restrict__ Wb0, const float* __restrict__ Wb1,
    const float* __restrict__ bb0, const float* __restrict__ bb1,
    float* __restrict__ ws)
{
    int bx = blockIdx.x;
    int s  = bx >> 7;
    int r  = bx & 127;
    int hc = r >> 2;
    int jc = r & 3;
    const float* Wb = s ? Wb1 : Wb0;
    const float* bb = s ? bb1 : bb0;
    const float* u  = ws + (s ? OFF_U1 : OFF_U0) + hc * 32;
    float* S = ws + (s ? OFF_S1 : OFF_S0);
    float sy = ws[OFF_SY + s];

    __shared__ float uL[32];
    int tid = threadIdx.x;
    if (tid < 32) uL[tid] = u[tid];
    __syncthreads();

    int j = jc * 1024 + tid * 4;
    float4 acc;
    if (hc == 0) {
        float4 b4 = *reinterpret_cast<const float4*>(bb + j);
        acc = make_float4(sy*b4.x, sy*b4.y, sy*b4.z, sy*b4.w);
    } else {
        acc = make_float4(0.f, 0.f, 0.f, 0.f);
    }

    const float* row = Wb + (hc * 32) * 4096 + j;
    #pragma unroll 8
    for (int h = 0; h < 32; ++h) {
        float4 w = *reinterpret_cast<const float4*>(row);
        float uh = uL[h];
        acc.x = fmaf(uh, w.x, acc.x);
        acc.y = fmaf(uh, w.y, acc.y);
        acc.z = fmaf(uh, w.z, acc.z);
        acc.w = fmaf(uh, w.w, acc.w);
        row += 4096;
    }
    atomicAdd(&S[j+0], acc.x);
    atomicAdd(&S[j+1], acc.y);
    atomicAdd(&S[j+2], acc.z);
    atomicAdd(&S[j+3], acc.w);
}

// K3: rhs[b*64+d] = sum_x S0[b,x]*S1[d,x].  grid = 16 blocks, 1 output/thread.
__global__ __launch_bounds__(256) void k3(float* __restrict__ ws)
{
    __shared__ float S0L[4096];
    __shared__ float S1T[64 * 65];   // transposed + pad: conflict-free
    const float* S0 = ws + OFF_S0;
    const float* S1 = ws + OFF_S1;
    float* rhs = ws + OFF_RHS;
    int tid = threadIdx.x;
    for (int i = tid; i < 4096; i += 256) {
        S0L[i] = S0[i];
        int d = i >> 6, x = i & 63;
        S1T[x * 65 + d] = S1[i];
    }
    __syncthreads();
    int o = blockIdx.x * 256 + tid;
    int b = o >> 6, d = o & 63;
    float acc = 0.0f;
    #pragma unroll 8
    for (int x = 0; x < 64; ++x)
        acc = fmaf(S0L[b*64 + x], S1T[x*65 + d], acc);   // broadcast * consec-bank
    rhs[o] = acc;
}

// K4: w2r[h] = Wx2[h,:]@rhs (1024 rows), c = bx2@rhs.  1 wave/row, grid = 257.
__global__ __launch_bounds__(256) void k4(
    const float* __restrict__ Wx2, const float* __restrict__ bx2,
    float* __restrict__ ws)
{
    __shared__ float4 rhsL[1024];
    const float4* rhs4 = reinterpret_cast<const float4*>(ws + OFF_RHS);
    int tid = threadIdx.x;
    for (int i = tid; i < 1024; i += 256) rhsL[i] = rhs4[i];
    __syncthreads();
    int wave = tid >> 6, lane = tid & 63;
    int rowIdx = blockIdx.x * 4 + wave;
    if (rowIdx > 1024) return;
    const float4* src4 = reinterpret_cast<const float4*>(
        (rowIdx < 1024) ? (Wx2 + rowIdx * 4096) : bx2);
    float acc = 0.0f;
    #pragma unroll
    for (int i = 0; i < 16; ++i) {
        float4 w = src4[lane + 64*i];
        float4 rv = rhsL[lane + 64*i];
        acc += w.x*rv.x + w.y*rv.y + w.z*rv.z + w.w*rv.w;
    }
    #pragma unroll
    for (int off = 32; off > 0; off >>= 1)
        acc += __shfl_down(acc, off);
    if (lane == 0) {
        if (rowIdx < 1024) ws[OFF_W2R + rowIdx] = acc;
        else               ws[OFF_C] = acc;
    }
}

// K5: out[n] = tanh(input[n]@Wx1 + bx1) @ w2r + c.
// 64 rows/block, 4 lanes/row (h = 4*i + p), grid = N/64.
__global__ __launch_bounds__(256) void k5(
    const float* __restrict__ input, const float* __restrict__ Wx1,
    const float* __restrict__ bx1, const float* __restrict__ ws,
    float* __restrict__ out, int N)
{
    __shared__ float4 WL[1024];     // {Wx1[0,h], Wx1[1,h], Wx1[2,h], bx1[h]}
    __shared__ float w2rL[1024];
    int tid = threadIdx.x;
    #pragma unroll
    for (int k = 0; k < 4; ++k) {
        int h = tid + 256*k;
        WL[h] = make_float4(Wx1[h], Wx1[1024 + h], Wx1[2048 + h], bx1[h]);
        w2rL[h] = ws[OFF_W2R + h];
    }
    __syncthreads();
    int n = blockIdx.x * 64 + (tid >> 2);
    int p = tid & 3;
    int nc = (n < N) ? n : (N - 1);
    float in0 = input[nc*3+0], in1 = input[nc*3+1], in2 = input[nc*3+2];
    float acc = 0.0f;
    #pragma unroll 4
    for (int i = 0; i < 256; ++i) {
        int h = 4*i + p;
        float4 w = WL[h];
        float z = fmaf(in0, w.x, fmaf(in1, w.y, fmaf(in2, w.z, w.w)));
        acc = fmaf(tanh_fast(z), w2rL[h], acc);
    }
    acc += __shfl_xor(acc, 1);
    acc += __shfl_xor(acc, 2);
    if (p == 0 && n < N) out[n] = acc + ws[OFF_C];
}

extern "C" void kernel_launch(void* const* d_in, const int* in_sizes, int n_in,
                              void* d_out, int out_size, void* d_ws, size_t ws_size,
                              hipStream_t stream)
{
    const float* input = (const float*)d_in[0];
    const float* eqp   = (const float*)d_in[1];
    const float* qx0   = (const float*)d_in[2];
    const float* qx1   = (const float*)d_in[3];
    const float* Wx1   = (const float*)d_in[4];
    const float* bx1   = (const float*)d_in[5];
    const float* Wx2   = (const float*)d_in[6];
    const float* bx2   = (const float*)d_in[7];
    const float* Wq0a  = (const float*)d_in[8];
    const float* bq0a  = (const float*)d_in[9];
    const float* Wq0b  = (const float*)d_in[10];
    const float* bq0b  = (const float*)d_in[11];
    const float* Wq1a  = (const float*)d_in[12];
    const float* bq1a  = (const float*)d_in[13];
    const float* Wq1b  = (const float*)d_in[14];
    const float* bq1b  = (const float*)d_in[15];
    float* ws  = (float*)d_ws;
    float* out = (float*)d_out;

    int N  = in_sizes[0] / 3;
    int NQ = in_sizes[2] / 3;
    int achunks = NQ / 64;   // 64

    hipMemsetAsync(d_ws, 0, MEMSET_FLOATS * sizeof(float), stream);
    hipLaunchKernelGGL(k1, dim3(2 * achunks), dim3(256), 0, stream,
                       qx0, qx1, Wq0a, Wq1a, bq0a, bq1a, eqp, ws, achunks);
    hipLaunchKernelGGL(k2, dim3(256), dim3(256), 0, stream,
                       Wq0b, Wq1b, bq0b, bq1b, ws);
    hipLaunchKernelGGL(k3, dim3(16), dim3(256), 0, stream, ws);
    hipLaunchKernelGGL(k4, dim3(257), dim3(256), 0, stream, Wx2, bx2, ws);
    hipLaunchKernelGGL(k5, dim3((N + 63) / 64), dim3(256), 0, stream,
                       input, Wx1, bx1, ws, out, N);
}